// Round 10
// baseline (2422.240 us; speedup 1.0000x reference)
//
#include <hip/hip_runtime.h>
#include <math.h>

#define BATCH 256
#define CH 512
#define SE_CH 32
#define HW 1024
#define NBLK 256
#define GS 32                 // blocks per group (own one batch-set)
#define BPG 32                // batches per group
#define PPB 16                // planes (channels) per block per batch
#define PPR 4                 // planes per round
#define RPB 4                 // rounds per batch
#define RT (BPG * RPB)        // 128 compute rounds
#define LAG 6                 // tail lag in rounds
#define RING 8                // LDS ring slots (8 x 16 KB = 128 KB)

typedef float f32x4 __attribute__((ext_vector_type(4)));

__device__ __forceinline__ void gload_lds16(const float* gsrc, float* ldst) {
    __builtin_amdgcn_global_load_lds(
        (const __attribute__((address_space(1))) void*)gsrc,
        (__attribute__((address_space(3))) void*)ldst, 16, 0, 0);
}

// One-pass SE: x read once (HBM->LDS), applied from LDS, written once.
// 256 blocks x 1024 threads, 1 block/CU (128+ KB LDS) -> all co-resident.
__global__ __launch_bounds__(1024, 1) void se_ldspipe(
        const float* __restrict__ x,
        float* __restrict__ out,
        const float* __restrict__ fc1_w,   // [SE_CH][CH]
        const float* __restrict__ fc1_b,   // [SE_CH]
        const float* __restrict__ fc2_w,   // [2*CH][SE_CH]
        const float* __restrict__ fc2_b,   // [2*CH]
        int* __restrict__ flags,           // [BATCH] zeroed per call
        int* __restrict__ flags2,          // [BATCH] zeroed per call
        float* __restrict__ sev_g,         // [BATCH][SE_CH]
        float* __restrict__ part) {        // [BATCH][GS][SE_CH]
    const int t = threadIdx.x;
    const int w = t >> 6;           // wave 0..15
    const int lane = t & 63;
    const int bid = (int)blockIdx.x;
    const int g = bid >> 5;         // group 0..7
    const int lb = bid & 31;        // block-in-group
    const int b0 = g * BPG;         // first batch of group
    const int pw = w >> 2;          // apply: plane within round
    const int qw = w & 3;           // apply: quarter of plane
    const int o32 = lane & 31;

    __shared__ __align__(16) float ring[RING][PPR][HW];      // 128 KB
    __shared__ float accp[2][RPB][PPR][SE_CH];               // 4 KB, batch-parity dbuf

    // ---- hoist all FC weights (zero global weight loads in the loop) ----
    const float fb1 = fc1_b[o32];
    float w1h0 = 0.f, w1h1 = 0.f, w1h2 = 0.f, w1h3 = 0.f;
    if (w < 4) {   // means wave w handles channel lb*16 + q4*4 + w
        const float* p1 = fc1_w + o32 * CH + lb * PPB + w;
        w1h0 = p1[0]; w1h1 = p1[PPR]; w1h2 = p1[2 * PPR]; w1h3 = p1[3 * PPR];
    }
    const int cbase = lb * PPB + pw;
    float w2h0, w2h1, w2h2, w2h3, b2h0, b2h1, b2h2, b2h3;
    {
        int c_, row;
        c_ = cbase + 0 * PPR; row = (lane < 32) ? c_ : CH + c_;
        w2h0 = fc2_w[row * SE_CH + o32]; b2h0 = fc2_b[row];
        c_ = cbase + 1 * PPR; row = (lane < 32) ? c_ : CH + c_;
        w2h1 = fc2_w[row * SE_CH + o32]; b2h1 = fc2_b[row];
        c_ = cbase + 2 * PPR; row = (lane < 32) ? c_ : CH + c_;
        w2h2 = fc2_w[row * SE_CH + o32]; b2h2 = fc2_b[row];
        c_ = cbase + 3 * PPR; row = (lane < 32) ? c_ : CH + c_;
        w2h3 = fc2_w[row * SE_CH + o32]; b2h3 = fc2_b[row];
    }

    // ---- prologue: prefetch round 0 (16 KB, wave w loads 1 KB) ----
    {
        const size_t bp0 = ((size_t)b0 * CH + lb * PPB) * HW;
        gload_lds16(x + bp0 + w * 256 + lane * 4, &ring[0][0][0] + w * 256);
    }

    float sevreg = 0.f;

#pragma clang loop unroll(disable)
    for (int r = 0; r < RT + LAG; ++r) {
        // wait pf(r): outstanding = [gload(r), apply-store(r-7)] -> vmcnt(1)
        if (r < RT) {
            if (r >= 7) asm volatile("s_waitcnt vmcnt(1)" ::: "memory");
            else        asm volatile("s_waitcnt vmcnt(0)" ::: "memory");
        }
        asm volatile("s_waitcnt lgkmcnt(0)" ::: "memory");
        __builtin_amdgcn_s_barrier();      // the ONE barrier per round

        // ---- partial-store: wave 15, at round 4j+4 (batch j's FC1 done) ----
        if (w == 15 && r >= 4 && ((r - 4) & 3) == 0) {
            const int j = (r - 4) >> 2;
            if (j < BPG && lane < 32) {
                float psum = 0.f;
#pragma unroll
                for (int q4 = 0; q4 < RPB; ++q4)
#pragma unroll
                    for (int pp = 0; pp < PPR; ++pp)
                        psum += accp[j & 1][q4][pp][lane];
                const int gb = b0 + j;
                __hip_atomic_store(&part[((size_t)gb * GS + lb) * SE_CH + lane],
                                   psum, __ATOMIC_RELAXED, __HIP_MEMORY_SCOPE_AGENT);
                if (lane == 0)
                    __hip_atomic_fetch_add(&flags[gb], 1, __ATOMIC_RELEASE,
                                           __HIP_MEMORY_SCOPE_AGENT);
            }
        }

        // ---- reducer: wave 14 of block lb==j, at round 4j+5 (1 rnd slack) ----
        if (w == 14 && r >= 5 && ((r - 5) & 3) == 0) {
            const int j = (r - 5) >> 2;
            if (j < BPG && lb == j) {
                const int gb = b0 + j;
                while (__hip_atomic_load(&flags[gb], __ATOMIC_ACQUIRE,
                                         __HIP_MEMORY_SCOPE_AGENT) < GS)
                    __builtin_amdgcn_s_sleep(2);
                const int h = lane >> 5;
                float tot = 0.f;
#pragma unroll
                for (int i2 = 0; i2 < 16; ++i2)
                    tot += __hip_atomic_load(
                        &part[((size_t)gb * GS + h * 16 + i2) * SE_CH + o32],
                        __ATOMIC_RELAXED, __HIP_MEMORY_SCOPE_AGENT);
                tot += __shfl_xor(tot, 32, 64);
                const float sv = fmaxf(tot + fb1, 0.f);
                if (lane < 32)
                    __hip_atomic_store(&sev_g[gb * SE_CH + lane], sv,
                                       __ATOMIC_RELAXED, __HIP_MEMORY_SCOPE_AGENT);
                if (lane == 0)
                    __hip_atomic_fetch_add(&flags2[gb], 1, __ATOMIC_RELEASE,
                                           __HIP_MEMORY_SCOPE_AGENT);
            }
        }

        // ---- tail sev fetch (first tail round of each batch; 1 rnd slack) ----
        const int tr = r - LAG;
        if (tr >= 0 && (tr & 3) == 0) {
            const int gbt = b0 + (tr >> 2);
            while (__hip_atomic_load(&flags2[gbt], __ATOMIC_ACQUIRE,
                                     __HIP_MEMORY_SCOPE_AGENT) < 1)
                __builtin_amdgcn_s_sleep(2);
            sevreg = __hip_atomic_load(&sev_g[gbt * SE_CH + o32],
                                       __ATOMIC_RELAXED, __HIP_MEMORY_SCOPE_AGENT);
        }

        // ---- means + FC1 contribution: waves 0..3 (plane = w) ----
        if (r < RT && w < 4) {
            const float* bp = &ring[r & 7][w][0];
            float ssum = 0.f;
#pragma unroll
            for (int s4 = 0; s4 < 4; ++s4) {
                f32x4 v = *(const f32x4*)(bp + s4 * 256 + lane * 4);
                ssum += (v.x + v.y) + (v.z + v.w);
            }
#pragma unroll
            for (int off = 32; off; off >>= 1)
                ssum += __shfl_xor(ssum, off, 64);
            const float mean = ssum * (1.0f / 1024.0f);
            const int q4 = r & 3;
            const float w1c = (q4 & 2) ? ((q4 & 1) ? w1h3 : w1h2)
                                       : ((q4 & 1) ? w1h1 : w1h0);
            if (lane < 32)
                accp[(r >> 2) & 1][q4][w][lane] = w1c * mean;
        }

        // ---- prefetch round r+1 (slot (r+1)&7; WAR-safe vs apply(r-6)) ----
        if (r + 1 < RT) {
            const int rn = r + 1;
            const size_t bpn =
                ((size_t)(b0 + (rn >> 2)) * CH + lb * PPB + (rn & 3) * PPR) * HW;
            gload_lds16(x + bpn + w * 256 + lane * 4,
                        &ring[rn & 7][0][0] + w * 256);
        }

        // ---- tail FC2 + apply(tr) from LDS, NT store ----
        if (tr >= 0) {
            const int q4t = tr & 3;
            const float w2c = (q4t & 2) ? ((q4t & 1) ? w2h3 : w2h2)
                                        : ((q4t & 1) ? w2h1 : w2h0);
            const float b2c = (q4t & 2) ? ((q4t & 1) ? b2h3 : b2h2)
                                        : ((q4t & 1) ? b2h1 : b2h0);
            float prod = w2c * sevreg;
#pragma unroll
            for (int off = 16; off; off >>= 1)
                prod += __shfl_xor(prod, off, 64);
            const float vpre = prod + b2c;
            const float vcross = __shfl_xor(vpre, 32, 64);
            const float spre = (lane < 32) ? vpre : vcross;
            const float bpre = (lane < 32) ? vcross : vpre;
            const float sg = 1.0f / (1.0f + expf(-spre));

            const float* ap = &ring[tr & 7][pw][qw * 256];
            f32x4 v = *(const f32x4*)(ap + lane * 4);
            f32x4 rr;
            rr.x = fmaf(v.x, sg, bpre);
            rr.y = fmaf(v.y, sg, bpre);
            rr.z = fmaf(v.z, sg, bpre);
            rr.w = fmaf(v.w, sg, bpre);
            const size_t gpt =
                (size_t)(b0 + (tr >> 2)) * CH + lb * PPB + q4t * PPR + pw;
            __builtin_nontemporal_store(
                rr, (f32x4*)(out + gpt * HW + qw * 256 + lane * 4));
        }
    }
}

extern "C" void kernel_launch(void* const* d_in, const int* in_sizes, int n_in,
                              void* d_out, int out_size, void* d_ws, size_t ws_size,
                              hipStream_t stream) {
    const float* x     = (const float*)d_in[0];
    const float* fc1_w = (const float*)d_in[1];
    const float* fc1_b = (const float*)d_in[2];
    const float* fc2_w = (const float*)d_in[3];
    const float* fc2_b = (const float*)d_in[4];
    float* out = (float*)d_out;

    int* flags   = (int*)d_ws;                       // 256 int
    int* flags2  = flags + 256;                      // 256 int
    float* sev_g = (float*)(flags2 + 256);           // 256*32 f32
    float* part  = sev_g + BATCH * SE_CH;            // 256*32*32 f32 (1 MB)

    hipMemsetAsync(d_ws, 0, 2048, stream);           // zero the two flag arrays

    se_ldspipe<<<NBLK, 1024, 0, stream>>>(x, out, fc1_w, fc1_b, fc2_w, fc2_b,
                                          flags, flags2, sev_g, part);
}

// Round 11
// 411.065 us; speedup vs baseline: 5.8926x; 5.8926x over previous
//
#include <hip/hip_runtime.h>
#include <math.h>

#define BATCH 256
#define CH 512
#define SE_CH 32
#define HW 1024            // 32*32 floats per plane
#define HALF 256           // channels per unit (half a batch = 1 MB)
#define NBLK 256           // one block per CU -> all co-resident, spin-safe
#define ROUNDS 2           // 512 units / 256 blocks

typedef float f32x4 __attribute__((ext_vector_type(4)));

#define FOR16(X) X(0) X(1) X(2) X(3) X(4) X(5) X(6) X(7) \
                 X(8) X(9) X(10) X(11) X(12) X(13) X(14) X(15)

// One-pass SE: x read once into NAMED registers (no array -> no scratch),
// 32-float cross-block FC1 exchange (2 per block total), apply from registers.
// HBM traffic = 512 MB in + 512 MB out.
__global__ __launch_bounds__(1024)
__attribute__((amdgpu_waves_per_eu(4, 4)))
void se_onepass_reg(
        const float* __restrict__ x,
        float* __restrict__ out,
        const float* __restrict__ fc1_w,   // [SE_CH][CH]
        const float* __restrict__ fc1_b,   // [SE_CH]
        const float* __restrict__ fc2_w,   // [2*CH][SE_CH]
        const float* __restrict__ fc2_b,   // [2*CH]
        float* __restrict__ yacc,          // [BATCH][SE_CH], zeroed per call
        int* __restrict__ flags) {         // [BATCH], zeroed per call
    const int t = threadIdx.x;
    const int wave = t >> 6;       // 0..15
    const int lane = t & 63;

    __shared__ float m[HALF];      // plane means of this half
    __shared__ float sev[SE_CH];   // relu(FC1) vector
    __shared__ float sc[HALF];     // sigmoid(scale) per local channel
    __shared__ float bo[HALF];     // bias per local channel

#pragma clang loop unroll(disable)
    for (int r = 0; r < ROUNDS; ++r) {
        const int unit = (int)blockIdx.x + NBLK * r;   // 0..511
        const int b = unit >> 1;                       // batch element
        const int h = unit & 1;                        // which half of channels
        const size_t base = ((size_t)b * CH + (size_t)h * HALF) * HW;
        const f32x4* xb = (const f32x4*)(x + base);
        f32x4* ob = (f32x4*)(out + base);

        // ---- 64 named f32x4 registers: wave owns planes wave*16..+15,
        //      lane holds f32x4 slots {lane, lane+64, lane+128, lane+192} ----
#define DECLP(p) f32x4 d##p##_0, d##p##_1, d##p##_2, d##p##_3;
        FOR16(DECLP)
#undef DECLP

#define LOADP(p) \
        d##p##_0 = __builtin_nontemporal_load(&xb[(size_t)(wave * 16 + (p)) * 256 +   0 + lane]); \
        d##p##_1 = __builtin_nontemporal_load(&xb[(size_t)(wave * 16 + (p)) * 256 +  64 + lane]); \
        d##p##_2 = __builtin_nontemporal_load(&xb[(size_t)(wave * 16 + (p)) * 256 + 128 + lane]); \
        d##p##_3 = __builtin_nontemporal_load(&xb[(size_t)(wave * 16 + (p)) * 256 + 192 + lane]);
        FOR16(LOADP)
#undef LOADP

        // ---- per-plane means: 16 independent 64-lane xor reduces ----
#define MEANP(p) { \
        f32x4 s4 = (d##p##_0 + d##p##_1) + (d##p##_2 + d##p##_3); \
        float s = (s4.x + s4.y) + (s4.z + s4.w); \
        s += __shfl_xor(s, 32, 64); s += __shfl_xor(s, 16, 64); \
        s += __shfl_xor(s, 8, 64);  s += __shfl_xor(s, 4, 64); \
        s += __shfl_xor(s, 2, 64);  s += __shfl_xor(s, 1, 64); \
        if (lane == 0) m[wave * 16 + (p)] = s * (1.0f / 1024.0f); }
        FOR16(MEANP)
#undef MEANP
        __syncthreads();

        // ---- partial FC1 over this half's channels (o = wave*2 + lane-half) ----
        {
            const int o = wave * 2 + (lane >> 5);      // 0..31
            const int cl0 = lane & 31;
            const float* wr = fc1_w + (size_t)o * CH + (size_t)h * HALF;
            float acc = 0.0f;
#pragma unroll
            for (int k = 0; k < 8; ++k)
                acc = fmaf(wr[cl0 + 32 * k], m[cl0 + 32 * k], acc);
            acc += __shfl_xor(acc, 16, 64);
            acc += __shfl_xor(acc, 8, 64);
            acc += __shfl_xor(acc, 4, 64);
            acc += __shfl_xor(acc, 2, 64);
            acc += __shfl_xor(acc, 1, 64);
            if (cl0 == 0)
                __hip_atomic_fetch_add(&yacc[b * SE_CH + o], acc,
                                       __ATOMIC_RELAXED, __HIP_MEMORY_SCOPE_AGENT);
        }
        __syncthreads();   // all 16 waves' atomics issued & drained

        // ---- cross-block exchange: partner block holds the other half ----
        if (t == 0) {
            __hip_atomic_fetch_add(&flags[b], 1,
                                   __ATOMIC_RELEASE, __HIP_MEMORY_SCOPE_AGENT);
            while (__hip_atomic_load(&flags[b], __ATOMIC_ACQUIRE,
                                     __HIP_MEMORY_SCOPE_AGENT) < 2)
                __builtin_amdgcn_s_sleep(2);
        }
        __syncthreads();

        // ---- finish FC1 (bias + relu) ----
        if (t < SE_CH) {
            float y = __hip_atomic_load(&yacc[b * SE_CH + t],
                                        __ATOMIC_RELAXED, __HIP_MEMORY_SCOPE_AGENT);
            sev[t] = fmaxf(y + fc1_b[t], 0.0f);
        }
        __syncthreads();

        // ---- FC2 for this half's channels ----
        if (t < 2 * HALF) {
            const int cl = t & (HALF - 1);
            const int row = (t < HALF) ? (h * HALF + cl) : (CH + h * HALF + cl);
            const float* wr = fc2_w + (size_t)row * SE_CH;
            float acc = fc2_b[row];
#pragma unroll
            for (int k = 0; k < SE_CH; ++k)
                acc = fmaf(wr[k], sev[k], acc);
            if (t < HALF)
                sc[cl] = 1.0f / (1.0f + expf(-acc));
            else
                bo[cl] = acc;
        }
        __syncthreads();

        // ---- apply from registers, nontemporal store ----
#define APPLYP(p) { \
        const float s_ = sc[wave * 16 + (p)]; \
        const float b_ = bo[wave * 16 + (p)]; \
        f32x4 rr; \
        rr.x = fmaf(d##p##_0.x, s_, b_); rr.y = fmaf(d##p##_0.y, s_, b_); \
        rr.z = fmaf(d##p##_0.z, s_, b_); rr.w = fmaf(d##p##_0.w, s_, b_); \
        __builtin_nontemporal_store(rr, &ob[(size_t)(wave * 16 + (p)) * 256 +   0 + lane]); \
        rr.x = fmaf(d##p##_1.x, s_, b_); rr.y = fmaf(d##p##_1.y, s_, b_); \
        rr.z = fmaf(d##p##_1.z, s_, b_); rr.w = fmaf(d##p##_1.w, s_, b_); \
        __builtin_nontemporal_store(rr, &ob[(size_t)(wave * 16 + (p)) * 256 +  64 + lane]); \
        rr.x = fmaf(d##p##_2.x, s_, b_); rr.y = fmaf(d##p##_2.y, s_, b_); \
        rr.z = fmaf(d##p##_2.z, s_, b_); rr.w = fmaf(d##p##_2.w, s_, b_); \
        __builtin_nontemporal_store(rr, &ob[(size_t)(wave * 16 + (p)) * 256 + 128 + lane]); \
        rr.x = fmaf(d##p##_3.x, s_, b_); rr.y = fmaf(d##p##_3.y, s_, b_); \
        rr.z = fmaf(d##p##_3.z, s_, b_); rr.w = fmaf(d##p##_3.w, s_, b_); \
        __builtin_nontemporal_store(rr, &ob[(size_t)(wave * 16 + (p)) * 256 + 192 + lane]); }
        FOR16(APPLYP)
#undef APPLYP
        // no trailing barrier needed: next round's m-writes are each wave's own
        // slots and are barrier-separated from every cross-wave m-read.
    }
}

extern "C" void kernel_launch(void* const* d_in, const int* in_sizes, int n_in,
                              void* d_out, int out_size, void* d_ws, size_t ws_size,
                              hipStream_t stream) {
    const float* x     = (const float*)d_in[0];
    const float* fc1_w = (const float*)d_in[1];
    const float* fc1_b = (const float*)d_in[2];
    const float* fc2_w = (const float*)d_in[3];
    const float* fc2_b = (const float*)d_in[4];
    float* out = (float*)d_out;

    float* yacc = (float*)d_ws;                                         // 32 KB
    int* flags  = (int*)((char*)d_ws + BATCH * SE_CH * sizeof(float));  // 1 KB

    hipMemsetAsync(d_ws, 0, BATCH * SE_CH * sizeof(float) + BATCH * sizeof(int),
                   stream);

    se_onepass_reg<<<NBLK, 1024, 0, stream>>>(x, out, fc1_w, fc1_b,
                                              fc2_w, fc2_b, yacc, flags);
}